// Round 5
// baseline (110.816 us; speedup 1.0000x reference)
//
#include <hip/hip_runtime.h>

#define N2 128
#define MM 16384
#define START 6
#define CB 32        // columns per block -> 512 blocks -> 2 blocks/CU
#define BT 512       // 8 waves = 16 half-wave shares (32 lanes each)
#define PROWS 136    // predT rows: 0..127 data, 128..135 zero
#define FROWS 152    // fTd rows: index = 16 + d; zero outside d in [2,127]

__global__ __launch_bounds__(BT, 4) void npi_fused(
    const float* __restrict__ rt, const float* __restrict__ dgt,
    const float* __restrict__ si, const float* __restrict__ f,
    const float* __restrict__ seed, float* __restrict__ out)
{
    __shared__ float predT[PROWS * CB];   // 17.0 KiB
    __shared__ float fTd[FROWS * CB];     // 19.0 KiB
    __shared__ float part[8 * 16 * CB];   // 16.0 KiB [wave][k][col]
    __shared__ float hrow[16 * CB];       //  2.0 KiB summed history
    __shared__ float si_s[N2];
    __shared__ float lred[8];

    const int t = threadIdx.x;
    const int c = t & (CB - 1);
    const int w = t >> 6;          // wave 0..7
    const int g = t >> 5;          // half-wave share 0..15
    const int hw = g & 1;
    const int m = blockIdx.x * CB + c;

    // f rows for this share -> registers; stream under phase 1.
    float fregs[8];
#pragma unroll
    for (int q = 0; q < 8; ++q)
        fregs[q] = f[((g << 3) + q) * MM + m];

    if (t < N2) si_s[t] = si[t];
    if (g < START) predT[(g << 5) + c] = seed[g * MM + m];
    if (g < 8) predT[((128 + g) << 5) + c] = 0.f;   // pred pad rows
    fTd[(g << 5) + c] = 0.f;                        // fTd idx 0..15
    if (g < 2) fTd[((16 + g) << 5) + c] = 0.f;      // idx 16,17 (d=0,1)
    if (g < 8) fTd[((144 + g) << 5) + c] = 0.f;     // idx 144..151

    float r16v[16];
    if (w == 0) {
#pragma unroll
        for (int k = 0; k < 16; ++k) r16v[k] = rt[k * MM + m];
    }
    __syncthreads();

    float sr[16];
#pragma unroll
    for (int k = 1; k < 16; ++k) sr[k] = si_s[k];

    // ---- phase 1, chunk 0: triangle from seeds (wave 0 only) ----
    if (w == 0) {
        float v[16];
#pragma unroll
        for (int k = 0; k < 16; ++k) {
            if (k < START) {
                v[k] = predT[(k << 5) + c];
            } else {
                float s = 0.f;
#pragma unroll
                for (int kk = 0; kk < 16; ++kk)
                    if (kk < k) s += v[kk] * sr[k - kk];
                v[k] = r16v[k] * s;
            }
        }
#pragma unroll
        for (int k = START; k < 16; ++k)
            if (hw == 0) predT[(k << 5) + c] = v[k];
#pragma unroll
        for (int k = 0; k < 16; ++k)              // prefetch chunk-1 rt
            r16v[k] = rt[(16 + k) * MM + m];
    }
    __syncthreads();

    // ---- phase 1, chunks b = 1..7: 16 equal j-shares of b each ----
    for (int b = 1; b < 8; ++b) {
        const int i0 = b << 4;
        const int jhi = b * (g + 1);              // share j in [jhi-b, jhi)
        const int base = i0 - jhi + 1;            // >= 1
        float c16[16];
#pragma unroll
        for (int e = 0; e < 16; ++e) c16[e] = si_s[base + e];
        float acc[16];
#pragma unroll
        for (int k = 0; k < 16; ++k) acc[k] = 0.f;
#pragma unroll
        for (int u = 0; u < 7; ++u) {             // b <= 7; uniform guard
            if (u < b) {
                float p = predT[((jhi - 1 - u) << 5) + c];
#pragma unroll
                for (int k = 0; k < 16; ++k)
                    acc[k] += p * c16[(u + k) & 15];
                if (u + 1 < b) c16[u & 15] = si_s[base + 16 + u];  // <=127
            }
        }
#pragma unroll
        for (int k = 0; k < 16; ++k)
            acc[k] += __shfl_xor(acc[k], 32, 64); // fold halves (free)
        if (hw == 0) {
#pragma unroll
            for (int k = 0; k < 16; ++k)
                part[(((w << 4) + k) << 5) + c] = acc[k];
        }
        __syncthreads();

        // stage B: 512 threads == 16k x 32c, one element each
        {
            float s = 0.f;
#pragma unroll
            for (int ww = 0; ww < 8; ++ww)
                s += part[(((ww << 4) + g) << 5) + c];
            hrow[(g << 5) + c] = s;
        }
        __syncthreads();

        // stage C: triangle on wave 0; rt prefetch flies across the barrier
        if (w == 0) {
            float v[16];
#pragma unroll
            for (int k = 0; k < 16; ++k) {
                float s = hrow[(k << 5) + c];
#pragma unroll
                for (int kk = 0; kk < 16; ++kk)
                    if (kk < k) s += v[kk] * sr[k - kk];
                v[k] = r16v[k] * s;
            }
#pragma unroll
            for (int k = 0; k < 8; ++k) {         // halves write 8 rows each
                float val = hw ? v[8 + k] : v[k];
                int row = i0 + (hw << 3) + k;
                predT[(row << 5) + c] = val;
            }
            if (b < 7) {
#pragma unroll
                for (int k = 0; k < 16; ++k)
                    r16v[k] = rt[(i0 + 16 + k) * MM + m];
            }
        }
        __syncthreads();
    }

    // ---- stage f -> LDS (loads long since landed) ----
#pragma unroll
    for (int q = 0; q < 8; ++q) {
        int d = (g << 3) + q;
        fTd[((16 + d) << 5) + c] = (d < 2) ? 0.f : fregs[q];
    }
    __syncthreads();

    // ---- phase 2: deaths conv + MSE ----
    float lsum = 0.f;
    if (g >= 10) {                                // rows 0..5 (one share each)
        int i = g - 10;
        float dv = dgt[i * MM + m];
        float e0 = (i == 0) ? (1e-9f - dv) : dv;
        lsum = e0 * e0;
    }

#pragma unroll
    for (int pass = 0; pass < 2; ++pass) {
        const int n = pass ? (15 - w) : w;        // pairs {w, 15-w}: 72 steps/wave
        const int i0 = START + (n << 3);          // 6..126
        const int jhi = i0 + 6;                   // even
        const int steps = jhi >> 1;               // equal per half (<= 66)
        const int jh = hw ? jhi : steps;
        const int fb = 17 + i0 - jh;              // ring base into fTd
        float cf[8];
#pragma unroll
        for (int e = 0; e < 8; ++e) cf[e] = fTd[((fb + e) << 5) + c];
        float acc8[8];
#pragma unroll
        for (int k = 0; k < 8; ++k) acc8[k] = 0.f;
        for (int sb = 0; sb < steps; sb += 8) {
#pragma unroll
            for (int u = 0; u < 8; ++u) {
                int s = sb + u;
                if (s < steps) {                  // uniform guard
                    float p = predT[((jh - 1 - s) << 5) + c];  // pad rows = 0
#pragma unroll
                    for (int k = 0; k < 8; ++k)
                        acc8[k] += p * cf[(u + k) & 7];
                    cf[u] = fTd[((fb + 8 + s) << 5) + c];      // max idx 150
                }
            }
        }
#pragma unroll
        for (int k = 0; k < 8; ++k)
            acc8[k] += __shfl_xor(acc8[k], 32, 64);
        if (hw == pass) {                         // one half finalizes each chunk
#pragma unroll
            for (int k = 0; k < 8; ++k) {
                int i = i0 + k;
                if (i < N2) {
                    float diff = acc8[k] - dgt[i * MM + m];
                    lsum += diff * diff;
                }
            }
        }
    }

    // ---- loss reduction ----
#pragma unroll
    for (int off = 32; off > 0; off >>= 1)
        lsum += __shfl_down(lsum, off, 64);
    if ((t & 63) == 0) lred[w] = lsum;
    __syncthreads();
    if (t == 0) {
        float tot = 0.f;
#pragma unroll
        for (int ww = 0; ww < 8; ++ww) tot += lred[ww];
        atomicAdd(out, tot * (1.0f / ((float)N2 * (float)MM)));
    }
}

extern "C" void kernel_launch(void* const* d_in, const int* in_sizes, int n_in,
                              void* d_out, int out_size, void* d_ws, size_t ws_size,
                              hipStream_t stream) {
    const float* rt   = (const float*)d_in[0];
    const float* dgt  = (const float*)d_in[1];
    const float* si   = (const float*)d_in[2];
    const float* f    = (const float*)d_in[3];
    const float* seed = (const float*)d_in[4];

    hipMemsetAsync(d_out, 0, sizeof(float), stream);
    npi_fused<<<dim3(MM / CB), dim3(BT), 0, stream>>>(
        rt, dgt, si, f, seed, (float*)d_out);
}